// Round 5
// baseline (604.641 us; speedup 1.0000x reference)
//
#include <hip/hip_runtime.h>

typedef _Float16 f16;
typedef _Float16 f16x8 __attribute__((ext_vector_type(8)));
typedef float f32x16 __attribute__((ext_vector_type(16)));

#define MFMA32(A, B, C) __builtin_amdgcn_mfma_f32_32x32x16_f16((A), (B), (C), 0, 0, 0)

__device__ __forceinline__ float sigm_(float x) {
    return __builtin_amdgcn_rcpf(1.f + __builtin_amdgcn_exp2f(-1.44269504088896f * x));
}
__device__ __forceinline__ float tanh_(float x) {
    float e = __builtin_amdgcn_exp2f(2.88539008177793f * x);   // e^(2x)
    return 1.f - 2.f * __builtin_amdgcn_rcpf(1.f + e);
}

// async global->LDS, 16B per lane (dest = wave-uniform base + lane*16)
__device__ __forceinline__ void stage16(const void* g, void* s) {
    __builtin_amdgcn_global_load_lds(
        (const __attribute__((address_space(1))) unsigned int*)(g),
        (__attribute__((address_space(3))) unsigned int*)(s), 16, 0, 0);
}

// Af XOR swizzle: row index for (kt, lp). Kills the 8-way bank conflict of
// the epilogue h-scatter (all groups aliased to banks 0-3); lane-uniform in
// e so vector b128 reads stay single-instruction.
__device__ __forceinline__ int afi(int kt, int lp) {
    return (kt << 6) + (lp ^ (((lp >> 3) ^ kt) & 7));
}

// ---- W_hh repack, kt-major: dst[((kt*32+nt)*64+lane)*8+e] = W[j][k]
//      j = nt*32+(lane&31), k = kt*16+((lane>>5)<<3)+e
__global__ void frag_conv_kt(const float* __restrict__ W, f16* __restrict__ dst) {
    int idx = blockIdx.x * blockDim.x + threadIdx.x;   // 512*512 = 262144 exact
    int e  = idx & 7;
    int lp = (idx >> 3) & 63;
    int nt = (idx >> 9) & 31;
    int kt = idx >> 14;
    int j = (nt << 5) + (lp & 31);
    int k = (kt << 4) + ((lp >> 5) << 3) + e;
    dst[idx] = (f16)W[j * 256 + k];
}

// ---- MLP weights: nt-major fragment layout (register path)
__global__ void frag_conv(const float* __restrict__ W, f16* __restrict__ dst, int total) {
    for (int idx = blockIdx.x * blockDim.x + threadIdx.x; idx < total;
         idx += gridDim.x * blockDim.x) {
        int e  = idx & 7;
        int lp = (idx >> 3) & 63;
        int kt = (idx >> 9) & 15;
        int nt = idx >> 13;
        int j = (nt << 5) + (lp & 31);
        int k = (kt << 4) + ((lp >> 5) << 3) + e;
        dst[idx] = (f16)W[j * 256 + k];
    }
}

#define STAGE4(PN, SRCOFF) do {                                              \
        const char* _g = sb + (SRCOFF);                                      \
        stage16(_g,         (PN) + st_o        );                            \
        stage16(_g +  8192, (PN) + st_o +  4096);                            \
        stage16(_g + 16384, (PN) + st_o +  8192);                            \
        stage16(_g + 24576, (PN) + st_o + 12288);                            \
    } while (0)

// NO per-phase barrier: each wave stages exactly the W chunks it reads back
// (self-producer/self-consumer), so W needs only the per-wave vmcnt(8).
// Issue-early: stage slice KT+2 first, then wait for slice KT (oldest 4).
#define PHASE(KT, PC, PN) do {                                               \
        STAGE4(PN, (((KT) + 2) & 15) * 32768);                               \
        asm volatile("s_waitcnt vmcnt(8)" ::: "memory");                     \
        f16x8 Av  = *(const f16x8*)(Acur + afi(KT, l) * 8);                  \
        f16x8 Bv0 = *(const f16x8*)((PC) + ((0 * 8 + w) << 9) + (l << 3));   \
        f16x8 Bv1 = *(const f16x8*)((PC) + ((1 * 8 + w) << 9) + (l << 3));   \
        f16x8 Bv2 = *(const f16x8*)((PC) + ((2 * 8 + w) << 9) + (l << 3));   \
        f16x8 Bv3 = *(const f16x8*)((PC) + ((3 * 8 + w) << 9) + (l << 3));   \
        acc0 = MFMA32(Av, Bv0, acc0);                                        \
        acc1 = MFMA32(Av, Bv1, acc1);                                        \
        acc2 = MFMA32(Av, Bv2, acc2);                                        \
        acc3 = MFMA32(Av, Bv3, acc3);                                        \
    } while (0)

__global__ __launch_bounds__(512)
void lstm_fused(const float* __restrict__ statf,   // [8192][256]
                const float* __restrict__ tfg,     // [8192][24]
                const float* __restrict__ tmg,     // [8192][24]
                const float* __restrict__ h0,      // [8192][256]
                const float* __restrict__ c0,      // [8192][256]
                const float* __restrict__ Wih,     // [1024][2]
                const float* __restrict__ bih,     // [1024]
                const float* __restrict__ bhh,     // [1024]
                const float* __restrict__ b1,
                const float* __restrict__ b2,
                const float* __restrict__ b3,
                const float* __restrict__ Wlr,     // [512]
                const float* __restrict__ blr,     // [1]
                const f16* __restrict__ WBH,       // kt-major W_hh frags (512 KB)
                const f16* __restrict__ WB1,       // nt-major W1 frags
                const f16* __restrict__ WB2,
                const f16* __restrict__ WB3,
                float* __restrict__ out)           // [8193]
{
    // 144 KB LDS total (1 block/CU):
    __shared__ __align__(16) f16 wsl[3][16384];    // 96 KB: 3 W-slice buffers
    __shared__ __align__(16) f16 Afb[2][1024][8];  // 32 KB: h fragments, double-buffered
    __shared__ float tf_l[32][24];                 // 3 KB
    __shared__ float tm_l[32][24];                 // 3 KB
    __shared__ float wlr_l[512];                   // 2 KB
    __shared__ f16   xa_l[1024];                   // 2 KB
    __shared__ f16   xb_l[1024];                   // 2 KB
    __shared__ float xc_l[1024];                   // 4 KB

    const int tid = threadIdx.x;
    const int w   = tid >> 6;       // wave 0..7
    const int l   = tid & 63;       // lane
    const int b0  = blockIdx.x * 32;

    // per-thread staging offsets (wave w owns chunks {w, 8+w, 16+w, 24+w})
    const char* sb  = (const char*)WBH + (w << 10) + (l << 4);
    const int   st_o = (w << 9) + (l << 3);                      // f16 elems

    // ---- issue prologue stages ASAP (slices 0,1) ----
    {
        f16* s0 = &wsl[0][0];
        f16* s1 = &wsl[1][0];
        #pragma unroll
        for (int i = 0; i < 4; ++i) stage16(sb + i * 8192,         s0 + st_o + i * 4096);
        #pragma unroll
        for (int i = 0; i < 4; ++i) stage16(sb + 32768 + i * 8192, s1 + st_o + i * 4096);
    }

    // ---------------- init fills ----------------
    for (int i = tid; i < 32 * 24; i += 512) {
        int r = i / 24, t = i - r * 24;
        tf_l[r][t] = tfg[(b0 + r) * 24 + t];
        tm_l[r][t] = tmg[(b0 + r) * 24 + t];
    }
    wlr_l[tid] = Wlr[tid];
    for (int i = tid; i < 1024; i += 512) {
        xa_l[i] = (f16)Wih[2 * i];
        xb_l[i] = (f16)Wih[2 * i + 1];
        xc_l[i] = bih[i] + bhh[i];
    }
    // h0 -> Afb[0] (swizzled rows)
    for (int i = tid; i < 1024; i += 512) {
        int fr = i >> 6, lp = i & 63;
        int row  = lp & 31;
        int koff = (fr << 4) + ((lp >> 5) << 3);
        const float4* s4 = (const float4*)&h0[(b0 + row) * 256 + koff];
        float4 a = s4[0], b = s4[1];
        f16x8 v;
        v[0]=(f16)a.x; v[1]=(f16)a.y; v[2]=(f16)a.z; v[3]=(f16)a.w;
        v[4]=(f16)b.x; v[5]=(f16)b.y; v[6]=(f16)b.z; v[7]=(f16)b.w;
        *(f16x8*)(&Afb[0][afi(fr, lp)][0]) = v;
    }

    // per-lane constants
    const int jc = (w << 5) + (l & 31);          // this lane's h/gate column
    float cst[16];
    #pragma unroll
    for (int reg = 0; reg < 16; ++reg) {
        int bl = (reg & 3) + ((reg >> 2) << 3) + ((l >> 5) << 2);
        cst[reg] = c0[(b0 + bl) * 256 + jc];
    }
    const int wkt    = jc >> 4;
    const int wlp_hi = ((l >> 3) & 1) << 5;
    const int we     = l & 7;
    const float xav0 = (float)xa_l[jc],       xav1 = (float)xa_l[256 + jc];
    const float xav2 = (float)xa_l[512 + jc], xav3 = (float)xa_l[768 + jc];
    const float xbv0 = (float)xb_l[jc],       xbv1 = (float)xb_l[256 + jc];
    const float xbv2 = (float)xb_l[512 + jc], xbv3 = (float)xb_l[768 + jc];

    // all init ds_writes visible to all waves before the loop
    asm volatile("s_waitcnt lgkmcnt(0)" ::: "memory");
    __builtin_amdgcn_s_barrier();
    const float xcv0 = xc_l[jc],       xcv1 = xc_l[256 + jc];
    const float xcv2 = xc_l[512 + jc], xcv3 = xc_l[768 + jc];

    f16* p0 = &wsl[0][0];
    f16* p1 = &wsl[1][0];
    f16* p2 = &wsl[2][0];

    // ---------------- LSTM over 24 steps: ONE barrier per step ----------------
    #pragma unroll 1
    for (int t = 0; t < 24; ++t) {
        f16* Acur = &Afb[t & 1][0][0];
        f16* Anxt = &Afb[(t + 1) & 1][0][0];
        f32x16 acc0, acc1, acc2, acc3;
        #pragma unroll
        for (int e = 0; e < 16; ++e) {
            acc0[e] = xcv0; acc1[e] = xcv1; acc2[e] = xcv2; acc3[e] = xcv3;
        }

        PHASE(0,  p0, p2);  PHASE(1,  p1, p0);  PHASE(2,  p2, p1);
        PHASE(3,  p0, p2);  PHASE(4,  p1, p0);  PHASE(5,  p2, p1);
        PHASE(6,  p0, p2);  PHASE(7,  p1, p0);  PHASE(8,  p2, p1);
        PHASE(9,  p0, p2);  PHASE(10, p1, p0);  PHASE(11, p2, p1);
        PHASE(12, p0, p2);  PHASE(13, p1, p0);  PHASE(14, p2, p1);
        PHASE(15, p0, p2);

        // epilogue: gates -> (c,h); write h into the OTHER Af buffer
        #pragma unroll
        for (int reg = 0; reg < 16; ++reg) {
            const int   bl  = (reg & 3) + ((reg >> 2) << 3) + ((l >> 5) << 2);
            const float tfv = tf_l[bl][t];
            const float tmv = tm_l[bl][t];
            float gi = acc0[reg] + xav0 * tfv + xbv0 * tmv;
            float gf = acc1[reg] + xav1 * tfv + xbv1 * tmv;
            float gg = acc2[reg] + xav2 * tfv + xbv2 * tmv;
            float go = acc3[reg] + xav3 * tfv + xbv3 * tmv;
            float i_ = sigm_(gi);
            float f_ = sigm_(gf);
            float g_ = tanh_(gg);
            float o_ = sigm_(go);
            float c_ = f_ * cst[reg] + i_ * g_;
            cst[reg] = c_;
            float h_ = o_ * tanh_(c_);
            Anxt[afi(wkt, bl | wlp_hi) * 8 + we] = (f16)h_;
        }
        // h writes visible to all waves; W stages stay in flight across it
        asm volatile("s_waitcnt lgkmcnt(0)" ::: "memory");
        __builtin_amdgcn_s_barrier();

        // rotate slice buffers (16 % 3 == 1)
        f16* tp = p0; p0 = p1; p1 = p2; p2 = tp;
    }
    // final h lives in Afb[0]

    // drain stray stages before reusing wsl as MLP buffers
    asm volatile("s_waitcnt vmcnt(0)" ::: "memory");
    __builtin_amdgcn_s_barrier();

    // ---------------- static MLP (register path for W) ----------------
    f16* A2 = &wsl[0][0];      // rows of 8 f16, afi-swizzled
    f16* A3 = &wsl[0][8192];

    for (int i = tid; i < 1024; i += 512) {
        int fr = i >> 6, lp = i & 63;
        int row  = lp & 31;
        int koff = (fr << 4) + ((lp >> 5) << 3);
        const float4* s4 = (const float4*)&statf[(b0 + row) * 256 + koff];
        float4 a = s4[0], b = s4[1];
        f16x8 v;
        v[0]=(f16)a.x; v[1]=(f16)a.y; v[2]=(f16)a.z; v[3]=(f16)a.w;
        v[4]=(f16)b.x; v[5]=(f16)b.y; v[6]=(f16)b.z; v[7]=(f16)b.w;
        *(f16x8*)(A2 + afi(fr, lp) * 8) = v;
    }
    __syncthreads();

    {
        const f16*   WBl[3]  = {WB1, WB2, WB3};
        const float* bls[3]  = {b1, b2, b3};
        f16*         ains[3] = {A2, A3, A2};
        f16*         aous[3] = {A3, A2, A3};
        const int lane8 = l << 3;
        #pragma unroll 1
        for (int layer = 0; layer < 3; ++layer) {
            const f16* WL  = WBl[layer];
            f16* ain  = ains[layer];
            f16* aout = aous[layer];
            float bias = bls[layer][jc];
            f32x16 acc2;
            #pragma unroll
            for (int e = 0; e < 16; ++e) acc2[e] = bias;

            f16x8 Bq[2], Aq2[2];
            Bq[0]  = *(const f16x8*)(WL + ((w * 16 + 0) * 512) + lane8);
            Aq2[0] = *(const f16x8*)(ain + afi(0, l) * 8);
            #pragma unroll
            for (int kt = 0; kt < 16; ++kt) {
                const int cb = kt & 1, nb = cb ^ 1;
                if (kt < 15) {
                    Bq[nb]  = *(const f16x8*)(WL + ((w * 16 + (kt + 1)) * 512) + lane8);
                    Aq2[nb] = *(const f16x8*)(ain + afi(kt + 1, l) * 8);
                }
                acc2 = MFMA32(Aq2[cb], Bq[cb], acc2);
            }
            __syncthreads();   // done reading ain before overwriting aout
            #pragma unroll
            for (int reg = 0; reg < 16; ++reg) {
                float v = acc2[reg];
                v = v > 0.f ? v : 0.f;
                const int bl2 = (reg & 3) + ((reg >> 2) << 3) + ((l >> 5) << 2);
                aout[afi(wkt, bl2 | wlp_hi) * 8 + we] = (f16)v;
            }
            __syncthreads();
        }
    }

    // ---------------- classifier: predicts = [h, s3] . Wlr + blr ----------------
    {
        const int r  = (w << 2) + (l >> 4);     // row 0..31
        const int lg = l & 15;
        const int lp = r | (((lg >> 3) & 1) << 5);
        const int ee = lg & 7;
        float sum = 0.f;
        #pragma unroll
        for (int i = 0; i < 16; ++i) {
            int j = lg + (i << 4);
            float hv = (float)Afb[0][afi(i, lp)][ee];
            float sv = (float)A3[afi(i, lp) * 8 + ee];
            sum += hv * wlr_l[j] + sv * wlr_l[256 + j];
        }
        sum += __shfl_xor(sum, 8);
        sum += __shfl_xor(sum, 4);
        sum += __shfl_xor(sum, 2);
        sum += __shfl_xor(sum, 1);
        if (lg == 0) out[b0 + r] = sum + blr[0];
    }
}

__global__ __launch_bounds__(1024)
void bce_kernel(const float* __restrict__ pred, const float* __restrict__ tgt,
                float* __restrict__ lossp) {
    const int tid = threadIdx.x;
    float acc = 0.f;
    for (int i = tid; i < 8192; i += 1024) {
        float p  = pred[i];
        float t  = tgt[i];
        float ax = fabsf(p);
        acc += fmaxf(p, 0.f) - p * t
             + log1pf(__builtin_amdgcn_exp2f(-1.44269504088896f * ax));
    }
    #pragma unroll
    for (int m = 32; m >= 1; m >>= 1) acc += __shfl_xor(acc, m);
    __shared__ float red[16];
    if ((tid & 63) == 0) red[tid >> 6] = acc;
    __syncthreads();
    if (tid < 16) {
        float v = red[tid];
        #pragma unroll
        for (int m = 8; m >= 1; m >>= 1) v += __shfl_xor(v, m);
        if (tid == 0) lossp[0] = v * (1.f / 8192.f);
    }
}

extern "C" void kernel_launch(void* const* d_in, const int* in_sizes, int n_in,
                              void* d_out, int out_size, void* d_ws, size_t ws_size,
                              hipStream_t stream) {
    const float* statf = (const float*)d_in[0];
    const float* tfg   = (const float*)d_in[1];
    const float* tmg   = (const float*)d_in[2];
    const float* tgt   = (const float*)d_in[3];
    const float* h0    = (const float*)d_in[4];
    const float* c0    = (const float*)d_in[5];
    const float* Wih   = (const float*)d_in[6];
    const float* Whh   = (const float*)d_in[7];
    const float* bih   = (const float*)d_in[8];
    const float* bhh   = (const float*)d_in[9];
    const float* W1    = (const float*)d_in[10];
    const float* b1    = (const float*)d_in[11];
    const float* W2    = (const float*)d_in[12];
    const float* b2    = (const float*)d_in[13];
    const float* W3    = (const float*)d_in[14];
    const float* b3    = (const float*)d_in[15];
    const float* Wlr   = (const float*)d_in[16];
    const float* blr   = (const float*)d_in[17];
    float* out = (float*)d_out;

    f16* WBH = (f16*)d_ws;            // 262144 halfs, kt-major
    f16* WB1 = WBH + 262144;          // 65536 halfs each, nt-major
    f16* WB2 = WB1 + 65536;
    f16* WB3 = WB2 + 65536;

    frag_conv_kt<<<512, 512, 0, stream>>>(Whh, WBH);
    frag_conv<<<128, 512, 0, stream>>>(W1, WB1, 65536);
    frag_conv<<<128, 512, 0, stream>>>(W2, WB2, 65536);
    frag_conv<<<128, 512, 0, stream>>>(W3, WB3, 65536);

    lstm_fused<<<256, 512, 0, stream>>>(statf, tfg, tmg, h0, c0, Wih, bih, bhh,
                                        b1, b2, b3, Wlr, blr,
                                        WBH, WB1, WB2, WB3, out);

    bce_kernel<<<1, 1024, 0, stream>>>(out, tgt, out + 8192);
}

// Round 7
// 315.574 us; speedup vs baseline: 1.9160x; 1.9160x over previous
//
#include <hip/hip_runtime.h>

typedef _Float16 f16;
typedef _Float16 f16x8 __attribute__((ext_vector_type(8)));
typedef float f32x16 __attribute__((ext_vector_type(16)));

#define MFMA32(A, B, C) __builtin_amdgcn_mfma_f32_32x32x16_f16((A), (B), (C), 0, 0, 0)

__device__ __forceinline__ float sigm_(float x) {
    return __builtin_amdgcn_rcpf(1.f + __builtin_amdgcn_exp2f(-1.44269504088896f * x));
}
__device__ __forceinline__ float tanh_(float x) {
    float e = __builtin_amdgcn_exp2f(2.88539008177793f * x);   // e^(2x)
    return 1.f - 2.f * __builtin_amdgcn_rcpf(1.f + e);
}

// async global->LDS, 16B per lane (dest = wave-uniform base + lane*16)
__device__ __forceinline__ void stage16(const void* g, void* s) {
    __builtin_amdgcn_global_load_lds(
        (const __attribute__((address_space(1))) unsigned int*)(g),
        (__attribute__((address_space(3))) unsigned int*)(s), 16, 0, 0);
}

// Af XOR swizzle: kills the 8-way bank conflict of the epilogue h-scatter
// (R4: 5.44M conflict cycles -> R5: 0). Lane-uniform in e -> b128 reads OK.
__device__ __forceinline__ int afi(int kt, int lp) {
    return (kt << 6) + (lp ^ (((lp >> 3) ^ kt) & 7));
}

// One prep kernel for all four weight repacks (was 4 launches, ~10us each).
// dst layout: [0, 262144)        = W_hh, kt-major slices
//             [262144 + s*65536) = W1/W2/W3, nt-major
__global__ void frag_conv_all(const float* __restrict__ Whh,
                              const float* __restrict__ W1,
                              const float* __restrict__ W2,
                              const float* __restrict__ W3,
                              f16* __restrict__ dst) {
    int idx = blockIdx.x * blockDim.x + threadIdx.x;   // 896*512 = 458752 exact
    if (idx < 262144) {
        int e  = idx & 7;
        int lp = (idx >> 3) & 63;
        int nt = (idx >> 9) & 31;
        int kt = idx >> 14;
        int j = (nt << 5) + (lp & 31);
        int k = (kt << 4) + ((lp >> 5) << 3) + e;
        dst[idx] = (f16)Whh[j * 256 + k];
    } else {
        int r   = idx - 262144;
        int sel = r >> 16;
        int i   = r & 65535;
        const float* W = (sel == 0) ? W1 : (sel == 1) ? W2 : W3;
        int e  = i & 7;
        int lp = (i >> 3) & 63;
        int kt = (i >> 9) & 15;
        int nt = i >> 13;
        int j = (nt << 5) + (lp & 31);
        int k = (kt << 4) + ((lp >> 5) << 3) + e;
        dst[idx] = (f16)W[j * 256 + k];
    }
}

#define STAGE4(PN, SRCOFF) do {                                              \
        const char* _g = sb + (SRCOFF);                                      \
        stage16(_g,         (PN) + st_o        );                            \
        stage16(_g +  8192, (PN) + st_o +  4096);                            \
        stage16(_g + 16384, (PN) + st_o +  8192);                            \
        stage16(_g + 24576, (PN) + st_o + 12288);                            \
    } while (0)

// W chunks are wave-private (wave w stages AND reads chunks {w,8+w,16+w,24+w})
// -> no barrier needed for W; per-wave counted vmcnt(8) suffices.
// sched_barrier(0) per phase: pins this phase's ds_reads+MFMAs together so the
// scheduler cannot double Bv/Av live ranges across phases (R5's spill cause).
#define PHASE(KT, PC, PN) do {                                               \
        STAGE4(PN, (((KT) + 2) & 15) * 32768);                               \
        asm volatile("s_waitcnt vmcnt(8)" ::: "memory");                     \
        __builtin_amdgcn_sched_barrier(0);                                   \
        f16x8 Av  = *(const f16x8*)(Acur + afi(KT, l) * 8);                  \
        f16x8 Bv0 = *(const f16x8*)((PC) + ((0 * 8 + w) << 9) + (l << 3));   \
        f16x8 Bv1 = *(const f16x8*)((PC) + ((1 * 8 + w) << 9) + (l << 3));   \
        f16x8 Bv2 = *(const f16x8*)((PC) + ((2 * 8 + w) << 9) + (l << 3));   \
        f16x8 Bv3 = *(const f16x8*)((PC) + ((3 * 8 + w) << 9) + (l << 3));   \
        acc0 = MFMA32(Av, Bv0, acc0);                                        \
        acc1 = MFMA32(Av, Bv1, acc1);                                        \
        acc2 = MFMA32(Av, Bv2, acc2);                                        \
        acc3 = MFMA32(Av, Bv3, acc3);                                        \
    } while (0)

__global__ __launch_bounds__(512)
void lstm_fused(const float* __restrict__ statf,   // [8192][256]
                const float* __restrict__ tfg,     // [8192][24]
                const float* __restrict__ tmg,     // [8192][24]
                const float* __restrict__ h0,      // [8192][256]
                const float* __restrict__ c0,      // [8192][256]
                const float* __restrict__ Wih,     // [1024][2]
                const float* __restrict__ bih,     // [1024]
                const float* __restrict__ bhh,     // [1024]
                const float* __restrict__ b1,
                const float* __restrict__ b2,
                const float* __restrict__ b3,
                const float* __restrict__ Wlr,     // [512]
                const float* __restrict__ blr,     // [1]
                const f16* __restrict__ WBH,       // kt-major W_hh frags (512 KB)
                const f16* __restrict__ WB1,       // nt-major W1 frags
                const f16* __restrict__ WB2,
                const f16* __restrict__ WB3,
                float* __restrict__ out)           // [8193]
{
    // 144 KB LDS total (1 block/CU):
    __shared__ __align__(16) f16 wsl[3][16384];    // 96 KB: 3 W-slice buffers
    __shared__ __align__(16) f16 Afb[2][1024][8];  // 32 KB: h fragments, double-buffered
    __shared__ float tf_l[32][24];                 // 3 KB
    __shared__ float tm_l[32][24];                 // 3 KB
    __shared__ float wlr_l[512];                   // 2 KB
    __shared__ f16   xa_l[1024];                   // 2 KB
    __shared__ f16   xb_l[1024];                   // 2 KB
    __shared__ float xc_l[1024];                   // 4 KB

    const int tid = threadIdx.x;
    const int w   = tid >> 6;       // wave 0..7
    const int l   = tid & 63;       // lane
    const int b0  = blockIdx.x * 32;

    // per-thread staging offsets (wave w owns chunks {w, 8+w, 16+w, 24+w})
    const char* sb  = (const char*)WBH + (w << 10) + (l << 4);
    const int   st_o = (w << 9) + (l << 3);                      // f16 elems

    // ---- issue prologue stages ASAP (slices 0,1) ----
    {
        f16* s0 = &wsl[0][0];
        f16* s1 = &wsl[1][0];
        #pragma unroll
        for (int i = 0; i < 4; ++i) stage16(sb + i * 8192,         s0 + st_o + i * 4096);
        #pragma unroll
        for (int i = 0; i < 4; ++i) stage16(sb + 32768 + i * 8192, s1 + st_o + i * 4096);
    }

    // ---------------- init fills ----------------
    for (int i = tid; i < 32 * 24; i += 512) {
        int r = i / 24, t = i - r * 24;
        tf_l[r][t] = tfg[(b0 + r) * 24 + t];
        tm_l[r][t] = tmg[(b0 + r) * 24 + t];
    }
    wlr_l[tid] = Wlr[tid];
    for (int i = tid; i < 1024; i += 512) {
        xa_l[i] = (f16)Wih[2 * i];
        xb_l[i] = (f16)Wih[2 * i + 1];
        xc_l[i] = bih[i] + bhh[i];
    }
    // h0 -> Afb[0] (swizzled rows)
    for (int i = tid; i < 1024; i += 512) {
        int fr = i >> 6, lp = i & 63;
        int row  = lp & 31;
        int koff = (fr << 4) + ((lp >> 5) << 3);
        const float4* s4 = (const float4*)&h0[(b0 + row) * 256 + koff];
        float4 a = s4[0], b = s4[1];
        f16x8 v;
        v[0]=(f16)a.x; v[1]=(f16)a.y; v[2]=(f16)a.z; v[3]=(f16)a.w;
        v[4]=(f16)b.x; v[5]=(f16)b.y; v[6]=(f16)b.z; v[7]=(f16)b.w;
        *(f16x8*)(&Afb[0][afi(fr, lp)][0]) = v;
    }

    // per-lane constants
    const int jc = (w << 5) + (l & 31);          // this lane's h/gate column
    float cst[16];
    #pragma unroll
    for (int reg = 0; reg < 16; ++reg) {
        int bl = (reg & 3) + ((reg >> 2) << 3) + ((l >> 5) << 2);
        cst[reg] = c0[(b0 + bl) * 256 + jc];
    }
    const int wkt    = jc >> 4;
    const int wlp_hi = ((l >> 3) & 1) << 5;
    const int we     = l & 7;

    // all init ds_writes visible to all waves before the loop
    asm volatile("s_waitcnt lgkmcnt(0)" ::: "memory");
    __builtin_amdgcn_s_barrier();

    f16* p0 = &wsl[0][0];
    f16* p1 = &wsl[1][0];
    f16* p2 = &wsl[2][0];

    // ---------------- LSTM over 24 steps: ONE barrier per step ----------------
    #pragma unroll 1
    for (int t = 0; t < 24; ++t) {
        f16* Acur = &Afb[t & 1][0][0];
        f16* Anxt = &Afb[(t + 1) & 1][0][0];
        f32x16 acc0, acc1, acc2, acc3;
        {
            const float xcv0 = xc_l[jc],       xcv1 = xc_l[256 + jc];
            const float xcv2 = xc_l[512 + jc], xcv3 = xc_l[768 + jc];
            #pragma unroll
            for (int e = 0; e < 16; ++e) {
                acc0[e] = xcv0; acc1[e] = xcv1; acc2[e] = xcv2; acc3[e] = xcv3;
            }
        }

        PHASE(0,  p0, p2);  PHASE(1,  p1, p0);  PHASE(2,  p2, p1);
        PHASE(3,  p0, p2);  PHASE(4,  p1, p0);  PHASE(5,  p2, p1);
        PHASE(6,  p0, p2);  PHASE(7,  p1, p0);  PHASE(8,  p2, p1);
        PHASE(9,  p0, p2);  PHASE(10, p1, p0);  PHASE(11, p2, p1);
        PHASE(12, p0, p2);  PHASE(13, p1, p0);  PHASE(14, p2, p1);
        PHASE(15, p0, p2);

        __builtin_amdgcn_sched_barrier(0);

        // epilogue: gates -> (c,h); x-consts re-read from LDS here (NOT loop-
        // carried: keeping them in registers across the K-loop caused spills)
        {
            const float xav0 = (float)xa_l[jc],       xav1 = (float)xa_l[256 + jc];
            const float xav2 = (float)xa_l[512 + jc], xav3 = (float)xa_l[768 + jc];
            const float xbv0 = (float)xb_l[jc],       xbv1 = (float)xb_l[256 + jc];
            const float xbv2 = (float)xb_l[512 + jc], xbv3 = (float)xb_l[768 + jc];
            #pragma unroll
            for (int reg = 0; reg < 16; ++reg) {
                const int   bl  = (reg & 3) + ((reg >> 2) << 3) + ((l >> 5) << 2);
                const float tfv = tf_l[bl][t];
                const float tmv = tm_l[bl][t];
                float gi = acc0[reg] + xav0 * tfv + xbv0 * tmv;
                float gf = acc1[reg] + xav1 * tfv + xbv1 * tmv;
                float gg = acc2[reg] + xav2 * tfv + xbv2 * tmv;
                float go = acc3[reg] + xav3 * tfv + xbv3 * tmv;
                float i_ = sigm_(gi);
                float f_ = sigm_(gf);
                float g_ = tanh_(gg);
                float o_ = sigm_(go);
                float c_ = f_ * cst[reg] + i_ * g_;
                cst[reg] = c_;
                float h_ = o_ * tanh_(c_);
                Anxt[afi(wkt, bl | wlp_hi) * 8 + we] = (f16)h_;
            }
        }
        // h writes visible to all waves; W stages stay in flight across this
        asm volatile("s_waitcnt lgkmcnt(0)" ::: "memory");
        __builtin_amdgcn_s_barrier();
        __builtin_amdgcn_sched_barrier(0);

        // rotate slice buffers (16 % 3 == 1)
        f16* tp = p0; p0 = p1; p1 = p2; p2 = tp;
    }
    // final h lives in Afb[0]

    // drain stray stages before reusing wsl as MLP buffers
    asm volatile("s_waitcnt vmcnt(0)" ::: "memory");
    __builtin_amdgcn_s_barrier();

    // ---------------- static MLP (register path for W) ----------------
    f16* A2 = &wsl[0][0];      // rows of 8 f16, afi-swizzled
    f16* A3 = &wsl[0][8192];

    for (int i = tid; i < 1024; i += 512) {
        int fr = i >> 6, lp = i & 63;
        int row  = lp & 31;
        int koff = (fr << 4) + ((lp >> 5) << 3);
        const float4* s4 = (const float4*)&statf[(b0 + row) * 256 + koff];
        float4 a = s4[0], b = s4[1];
        f16x8 v;
        v[0]=(f16)a.x; v[1]=(f16)a.y; v[2]=(f16)a.z; v[3]=(f16)a.w;
        v[4]=(f16)b.x; v[5]=(f16)b.y; v[6]=(f16)b.z; v[7]=(f16)b.w;
        *(f16x8*)(A2 + afi(fr, lp) * 8) = v;
    }
    __syncthreads();

    {
        const f16*   WBl[3]  = {WB1, WB2, WB3};
        const float* bls[3]  = {b1, b2, b3};
        f16*         ains[3] = {A2, A3, A2};
        f16*         aous[3] = {A3, A2, A3};
        const int lane8 = l << 3;
        #pragma unroll 1
        for (int layer = 0; layer < 3; ++layer) {
            const f16* WL  = WBl[layer];
            f16* ain  = ains[layer];
            f16* aout = aous[layer];
            float bias = bls[layer][jc];
            f32x16 acc2;
            #pragma unroll
            for (int e = 0; e < 16; ++e) acc2[e] = bias;

            f16x8 Bq[2], Aq2[2];
            Bq[0]  = *(const f16x8*)(WL + ((w * 16 + 0) * 512) + lane8);
            Aq2[0] = *(const f16x8*)(ain + afi(0, l) * 8);
            #pragma unroll
            for (int kt = 0; kt < 16; ++kt) {
                const int cb = kt & 1, nb = cb ^ 1;
                if (kt < 15) {
                    Bq[nb]  = *(const f16x8*)(WL + ((w * 16 + (kt + 1)) * 512) + lane8);
                    Aq2[nb] = *(const f16x8*)(ain + afi(kt + 1, l) * 8);
                }
                acc2 = MFMA32(Aq2[cb], Bq[cb], acc2);
            }
            __syncthreads();   // done reading ain before overwriting aout
            #pragma unroll
            for (int reg = 0; reg < 16; ++reg) {
                float v = acc2[reg];
                v = v > 0.f ? v : 0.f;
                const int bl2 = (reg & 3) + ((reg >> 2) << 3) + ((l >> 5) << 2);
                aout[afi(wkt, bl2 | wlp_hi) * 8 + we] = (f16)v;
            }
            __syncthreads();
        }
    }

    // ---------------- classifier: predicts = [h, s3] . Wlr + blr ----------------
    {
        const int r  = (w << 2) + (l >> 4);     // row 0..31
        const int lg = l & 15;
        const int lp = r | (((lg >> 3) & 1) << 5);
        const int ee = lg & 7;
        float sum = 0.f;
        #pragma unroll
        for (int i = 0; i < 16; ++i) {
            int j = lg + (i << 4);
            float hv = (float)Afb[0][afi(i, lp)][ee];
            float sv = (float)A3[afi(i, lp) * 8 + ee];
            sum += hv * wlr_l[j] + sv * wlr_l[256 + j];
        }
        sum += __shfl_xor(sum, 8);
        sum += __shfl_xor(sum, 4);
        sum += __shfl_xor(sum, 2);
        sum += __shfl_xor(sum, 1);
        if (lg == 0) out[b0 + r] = sum + blr[0];
    }
}

__global__ __launch_bounds__(1024)
void bce_kernel(const float* __restrict__ pred, const float* __restrict__ tgt,
                float* __restrict__ lossp) {
    const int tid = threadIdx.x;
    float acc = 0.f;
    for (int i = tid; i < 8192; i += 1024) {
        float p  = pred[i];
        float t  = tgt[i];
        float ax = fabsf(p);
        acc += fmaxf(p, 0.f) - p * t
             + log1pf(__builtin_amdgcn_exp2f(-1.44269504088896f * ax));
    }
    #pragma unroll
    for (int m = 32; m >= 1; m >>= 1) acc += __shfl_xor(acc, m);
    __shared__ float red[16];
    if ((tid & 63) == 0) red[tid >> 6] = acc;
    __syncthreads();
    if (tid < 16) {
        float v = red[tid];
        #pragma unroll
        for (int m = 8; m >= 1; m >>= 1) v += __shfl_xor(v, m);
        if (tid == 0) lossp[0] = v * (1.f / 8192.f);
    }
}

extern "C" void kernel_launch(void* const* d_in, const int* in_sizes, int n_in,
                              void* d_out, int out_size, void* d_ws, size_t ws_size,
                              hipStream_t stream) {
    const float* statf = (const float*)d_in[0];
    const float* tfg   = (const float*)d_in[1];
    const float* tmg   = (const float*)d_in[2];
    const float* tgt   = (const float*)d_in[3];
    const float* h0    = (const float*)d_in[4];
    const float* c0    = (const float*)d_in[5];
    const float* Wih   = (const float*)d_in[6];
    const float* Whh   = (const float*)d_in[7];
    const float* bih   = (const float*)d_in[8];
    const float* bhh   = (const float*)d_in[9];
    const float* W1    = (const float*)d_in[10];
    const float* b1    = (const float*)d_in[11];
    const float* W2    = (const float*)d_in[12];
    const float* b2    = (const float*)d_in[13];
    const float* W3    = (const float*)d_in[14];
    const float* b3    = (const float*)d_in[15];
    const float* Wlr   = (const float*)d_in[16];
    const float* blr   = (const float*)d_in[17];
    float* out = (float*)d_out;

    f16* WBH = (f16*)d_ws;            // 262144 halfs, kt-major
    f16* WB1 = WBH + 262144;          // 65536 halfs each, nt-major
    f16* WB2 = WB1 + 65536;
    f16* WB3 = WB2 + 65536;

    frag_conv_all<<<896, 512, 0, stream>>>(Whh, W1, W2, W3, WBH);

    lstm_fused<<<256, 512, 0, stream>>>(statf, tfg, tmg, h0, c0, Wih, bih, bhh,
                                        b1, b2, b3, Wlr, blr,
                                        WBH, WB1, WB2, WB3, out);

    bce_kernel<<<1, 1024, 0, stream>>>(out, tgt, out + 8192);
}